// Round 2
// baseline (5773.070 us; speedup 1.0000x reference)
//
#include <hip/hip_runtime.h>
#include <math.h>

// Dims (fixed by the problem)
#define HH   50          // hidden
#define GG   150         // 3H
#define XGS  152         // xg row stride (padded)
#define TTT  2048        // T
#define NB   64          // batch B
#define MTOT (TTT*NB)    // 131072 rows per layer
#define D0   128         // layer-0 input dim

static __device__ __forceinline__ float sigm(float x) {
    return 1.f / (1.f + __expf(-x));
}
static __device__ __forceinline__ float tanh_f(float x) {
    return 1.f - 2.f / (__expf(2.f * x) + 1.f);   // saturates correctly at +/-inf
}

static __device__ __forceinline__ void fma4(float4& a, float s, const float4& w) {
    a.x += s * w.x; a.y += s * w.y; a.z += s * w.z; a.w += s * w.w;
}

// ---------------- Layer-0 input projection: Xg = X0 @ W + bi ----------------
// 128 rows x 152(cols,padded) per block. Register tile 4 rows x 4 cols per
// item; items = 38 col-quads x 32 row-quads = 1216 over 256 threads (waves
// 0-2 carry a 5th item -> zero divergence). K quartered (32) so LDS < 64KB:
// xs[128][36] (stride 36 staggers banks; f4-aligned), Wp[32][152] row-padded
// so float4 col reads are aligned. Per 4k: 8 ds_read_b128 -> 64 FMAs.
__global__ __launch_bounds__(256) void proj0_kernel(
    const float* __restrict__ x,              // [64,2048,128] f32
    const float* __restrict__ W,              // [128,150] f32
    const float* __restrict__ bias,           // [2,150] f32 (bi = bias[0])
    float* __restrict__ xg)                   // [MTOT,XGS] f32
{
    __shared__ float xs[128][36];             // k-quarter of x, bank-staggered (18.4 KB)
    __shared__ float Wp[32][XGS];             // k-quarter of W, col-padded   (19.5 KB)
    const int tid = threadIdx.x;
    const int m0 = blockIdx.x * 128;

    int cgv[5], rgv[5];
    #pragma unroll
    for (int it = 0; it < 5; ++it) {
        int item = it * 256 + tid;            // < 1216 except it=4,tid>=192
        rgv[it] = item / 38;
        cgv[it] = item - rgv[it] * 38;
    }
    float4 acc[5][4];
    #pragma unroll
    for (int it = 0; it < 5; ++it)
        #pragma unroll
        for (int j = 0; j < 4; ++j) acc[it][j] = make_float4(0.f, 0.f, 0.f, 0.f);

    for (int q = 0; q < 4; ++q) {             // K quarters
        if (q) __syncthreads();
        // stage x quarter: coalesced f4 global, staggered LDS rows
        for (int i = tid; i < 128 * 8; i += 256) {
            int r = i >> 3, c4 = (i & 7) * 4;
            int row = m0 + r, t = row >> 6, b = row & 63;
            *(float4*)&xs[r][c4] =
                *(const float4*)&x[((size_t)b * TTT + t) * D0 + q * 32 + c4];
        }
        // stage W quarter (coalesced read, conflict-free LDS write)
        for (int i = tid; i < 32 * XGS; i += 256) {
            int k = i / XGS, c = i - k * XGS;
            Wp[k][c] = (c < GG) ? W[(q * 32 + k) * GG + c] : 0.f;
        }
        __syncthreads();
        #pragma unroll
        for (int it = 0; it < 5; ++it) {
            if (it == 4 && tid >= 192) continue;
            const int cg = cgv[it], rg = rgv[it];
            const float* xr0 = xs[rg * 4 + 0];
            const float* xr1 = xs[rg * 4 + 1];
            const float* xr2 = xs[rg * 4 + 2];
            const float* xr3 = xs[rg * 4 + 3];
            for (int kk = 0; kk < 32; kk += 4) {
                float4 w0 = *(const float4*)&Wp[kk + 0][cg * 4];
                float4 w1 = *(const float4*)&Wp[kk + 1][cg * 4];
                float4 w2 = *(const float4*)&Wp[kk + 2][cg * 4];
                float4 w3 = *(const float4*)&Wp[kk + 3][cg * 4];
                float4 x0 = *(const float4*)&xr0[kk];   // broadcast across cg lanes
                float4 x1 = *(const float4*)&xr1[kk];
                float4 x2 = *(const float4*)&xr2[kk];
                float4 x3 = *(const float4*)&xr3[kk];
                fma4(acc[it][0], x0.x, w0); fma4(acc[it][0], x0.y, w1);
                fma4(acc[it][0], x0.z, w2); fma4(acc[it][0], x0.w, w3);
                fma4(acc[it][1], x1.x, w0); fma4(acc[it][1], x1.y, w1);
                fma4(acc[it][1], x1.z, w2); fma4(acc[it][1], x1.w, w3);
                fma4(acc[it][2], x2.x, w0); fma4(acc[it][2], x2.y, w1);
                fma4(acc[it][2], x2.z, w2); fma4(acc[it][2], x2.w, w3);
                fma4(acc[it][3], x3.x, w0); fma4(acc[it][3], x3.y, w1);
                fma4(acc[it][3], x3.z, w2); fma4(acc[it][3], x3.w, w3);
            }
        }
    }
    #pragma unroll
    for (int it = 0; it < 5; ++it) {
        if (it == 4 && tid >= 192) continue;
        const int cg = cgv[it], rg = rgv[it];
        float4 bv = *(const float4*)&bias[cg * 4];   // cols>=150 land in xg pad (unread)
        #pragma unroll
        for (int j = 0; j < 4; ++j) {
            float4 o;
            o.x = acc[it][j].x + bv.x; o.y = acc[it][j].y + bv.y;
            o.z = acc[it][j].z + bv.z; o.w = acc[it][j].w + bv.w;
            *(float4*)&xg[(size_t)(m0 + rg * 4 + j) * XGS + cg * 4] = o;
        }
    }
}

// ---------------- Layers 1..5 input projection (K=50 padded to 52) ----------------
__global__ __launch_bounds__(256) void projH_kernel(
    const float* __restrict__ Xin,            // [MTOT,50] f32 time-major
    const float* __restrict__ W,              // [50,150] f32
    const float* __restrict__ bias,           // [2,150] f32
    float* __restrict__ xg)                   // [MTOT,XGS] f32
{
    __shared__ float xs[128][52];             // 26.6 KB, k padded with zeros
    __shared__ float Wp[52][XGS];             // 31.6 KB, zeros in pads
    const int tid = threadIdx.x;
    const int m0 = blockIdx.x * 128;

    for (int i = tid; i < 128 * 52; i += 256) {
        int r = i / 52, k = i - r * 52;
        xs[r][k] = (k < HH) ? Xin[(size_t)(m0 + r) * HH + k] : 0.f;
    }
    for (int i = tid; i < 52 * XGS; i += 256) {
        int k = i / XGS, c = i - k * XGS;
        Wp[k][c] = (k < HH && c < GG) ? W[k * GG + c] : 0.f;
    }
    __syncthreads();

    int cgv[5], rgv[5];
    #pragma unroll
    for (int it = 0; it < 5; ++it) {
        int item = it * 256 + tid;
        rgv[it] = item / 38;
        cgv[it] = item - rgv[it] * 38;
    }
    float4 acc[5][4];
    #pragma unroll
    for (int it = 0; it < 5; ++it)
        #pragma unroll
        for (int j = 0; j < 4; ++j) acc[it][j] = make_float4(0.f, 0.f, 0.f, 0.f);

    #pragma unroll
    for (int it = 0; it < 5; ++it) {
        if (it == 4 && tid >= 192) continue;
        const int cg = cgv[it], rg = rgv[it];
        const float* xr0 = xs[rg * 4 + 0];
        const float* xr1 = xs[rg * 4 + 1];
        const float* xr2 = xs[rg * 4 + 2];
        const float* xr3 = xs[rg * 4 + 3];
        for (int kk = 0; kk < 52; kk += 4) {   // 13 bundles; pads contribute 0
            float4 w0 = *(const float4*)&Wp[kk + 0][cg * 4];
            float4 w1 = *(const float4*)&Wp[kk + 1][cg * 4];
            float4 w2 = *(const float4*)&Wp[kk + 2][cg * 4];
            float4 w3 = *(const float4*)&Wp[kk + 3][cg * 4];
            float4 x0 = *(const float4*)&xr0[kk];
            float4 x1 = *(const float4*)&xr1[kk];
            float4 x2 = *(const float4*)&xr2[kk];
            float4 x3 = *(const float4*)&xr3[kk];
            fma4(acc[it][0], x0.x, w0); fma4(acc[it][0], x0.y, w1);
            fma4(acc[it][0], x0.z, w2); fma4(acc[it][0], x0.w, w3);
            fma4(acc[it][1], x1.x, w0); fma4(acc[it][1], x1.y, w1);
            fma4(acc[it][1], x1.z, w2); fma4(acc[it][1], x1.w, w3);
            fma4(acc[it][2], x2.x, w0); fma4(acc[it][2], x2.y, w1);
            fma4(acc[it][2], x2.z, w2); fma4(acc[it][2], x2.w, w3);
            fma4(acc[it][3], x3.x, w0); fma4(acc[it][3], x3.y, w1);
            fma4(acc[it][3], x3.z, w2); fma4(acc[it][3], x3.w, w3);
        }
    }
    #pragma unroll
    for (int it = 0; it < 5; ++it) {
        if (it == 4 && tid >= 192) continue;
        const int cg = cgv[it], rg = rgv[it];
        float4 bv = *(const float4*)&bias[cg * 4];
        #pragma unroll
        for (int j = 0; j < 4; ++j) {
            float4 o;
            o.x = acc[it][j].x + bv.x; o.y = acc[it][j].y + bv.y;
            o.z = acc[it][j].z + bv.z; o.w = acc[it][j].w + bv.w;
            *(float4*)&xg[(size_t)(m0 + rg * 4 + j) * XGS + cg * 4] = o;
        }
    }
}

// ---------------- GRU recurrence, barrier-free wave-autonomous (unchanged) ----------------
template<int WPB>
__global__ __launch_bounds__(WPB * 64) void gru_wave(
    const float* __restrict__ xg,             // [dn*Nbatch, XGS] f32 (includes bi)
    const float* __restrict__ U,              // [50,150] f32
    const float* __restrict__ bias,           // [2,150] f32 (br = bias+150)
    float* __restrict__ Xout,                 // [MTOT,50] f32 time-major
    int dn, int Nbatch)
{
    constexpr int R = 4 * WPB;                // rows per block
    __shared__ __align__(16) float Us[HH * XGS];      // 30.4 KB (cols padded to 152)
    __shared__ __align__(16) float brs[XGS];
    __shared__ __align__(16) float hsT[HH][R];        // transposed h, wave w owns cols 4w..4w+3
    __shared__ __align__(16) float rc[R][XGS];        // rec result, wave w owns rows 4w..4w+3

    const int tid  = threadIdx.x;
    const int wav  = tid >> 6;
    const int lane = tid & 63;

    for (int i = tid; i < HH * XGS; i += WPB * 64) {
        int c = i % XGS;
        Us[i] = (c < GG) ? U[(i / XGS) * GG + c] : 0.f;
    }
    for (int i = tid; i < XGS; i += WPB * 64) brs[i] = (i < GG) ? bias[GG + i] : 0.f;
    for (int i = tid; i < HH * R; i += WPB * 64) ((float*)hsT)[i] = 0.f;
    __syncthreads();                          // the only block-wide barrier

    const int cg = lane;                      // valid if < 38
    float4 brv = make_float4(0.f, 0.f, 0.f, 0.f);
    if (cg < 38) brv = *(const float4*)&brs[cg * 4];

    const int gr = lane >> 4;                 // 0..3 row within wave
    const int gk = lane & 15;
    const int nrow = blockIdx.x * R + wav * 4 + gr;
    const int jj = nrow >> 6, bb = nrow & 63;
    float hprev[4] = {0.f, 0.f, 0.f, 0.f};

    for (int s = 0; s < dn; ++s) {
        float pz[4], pr[4], ph[4];
        {
            const float* g = xg + ((size_t)s * Nbatch + nrow) * XGS;
            #pragma unroll
            for (int u = 0; u < 4; ++u) {
                int k = gk + 16 * u;
                if (k < HH) { pz[u] = g[k]; pr[u] = g[HH + k]; ph[u] = g[2 * HH + k]; }
            }
        }
        if (cg < 38) {
            float acc[4][4];
            #pragma unroll
            for (int j = 0; j < 4; ++j) {
                acc[j][0] = brv.x; acc[j][1] = brv.y; acc[j][2] = brv.z; acc[j][3] = brv.w;
            }
            #pragma unroll
            for (int k = 0; k < HH; ++k) {
                float4 w  = *(const float4*)&Us[k * XGS + cg * 4];
                float4 hv = *(const float4*)&hsT[k][wav * 4];
                float hj[4] = {hv.x, hv.y, hv.z, hv.w};
                float wc[4] = {w.x, w.y, w.z, w.w};
                #pragma unroll
                for (int j = 0; j < 4; ++j)
                    #pragma unroll
                    for (int c = 0; c < 4; ++c) acc[j][c] += hj[j] * wc[c];
            }
            #pragma unroll
            for (int j = 0; j < 4; ++j)
                *(float4*)&rc[wav * 4 + j][cg * 4] = *(const float4*)&acc[j][0];
        }
        const float* rcrow = rc[wav * 4 + gr];
        #pragma unroll
        for (int u = 0; u < 4; ++u) {
            int k = gk + 16 * u;
            if (k < HH) {
                float rcz = rcrow[k];
                float rcr = rcrow[HH + k];
                float rch = rcrow[2 * HH + k];
                float z  = sigm(pz[u] + rcz);
                float rr = sigm(pr[u] + rcr);
                float hh = tanh_f(ph[u] + rr * rch);
                float hn = z * hprev[u] + (1.f - z) * hh;
                hprev[u] = hn;
                hsT[k][wav * 4 + gr] = hn;
                Xout[((size_t)(jj * dn + s) * NB + bb) * HH + k] = hn;
            }
        }
    }
}

// ---------------- Head: split-K partial GEMM (no bias/relu here) ----------------
// grid (7, 8, 16): 896 blocks. part[kz][64][1600] partial sums over 100-feature
// slices. Deterministic (no atomics); reduction folded into cls_kernel.
__global__ __launch_bounds__(256) void dense2_kernel(
    const float* __restrict__ X,              // [MTOT,50] f32 final layer (time-major)
    const float* __restrict__ W2,             // [1600,1600] f32
    float* __restrict__ part)                 // [16,64,1600] f32 partials
{
    __shared__ float fs[8][100];              // 3.2 KB
    const int tid = threadIdx.x;
    const int c  = blockIdx.x * 256 + tid;
    const int r0 = blockIdx.y * 8;
    const int kz = blockIdx.z;
    for (int i = tid; i < 8 * 100; i += 256) {
        int r = i / 100, fl = i - r * 100;
        int f = kz * 100 + fl, j = f / HH, k = f - j * HH;
        fs[r][fl] = X[((size_t)(TTT - 32 + j) * NB + (r0 + r)) * HH + k];
    }
    __syncthreads();
    if (c < 1600) {
        float a[8] = {0, 0, 0, 0, 0, 0, 0, 0};
        const float* w = W2 + (size_t)kz * 100 * 1600 + c;
        for (int fl = 0; fl < 100; ++fl) {
            float wv = w[(size_t)fl * 1600];
            #pragma unroll
            for (int r = 0; r < 8; ++r) a[r] += fs[r][fl] * wv;
        }
        #pragma unroll
        for (int r = 0; r < 8; ++r)
            part[((size_t)kz * NB + r0 + r) * 1600 + c] = a[r];
    }
}

// ---------------- Classifier: sum partials + bias + relu, then softmax ----------------
__global__ __launch_bounds__(256) void cls_kernel(
    const float* __restrict__ part,           // [16,64,1600] f32 partials
    const float* __restrict__ b2,             // [1600] f32
    const float* __restrict__ Wc,             // [1600,41] f32
    const float* __restrict__ bc,             // [41] f32
    float* __restrict__ out)                  // [64,41] f32
{
    __shared__ float hrow[1600];
    __shared__ float lg[41];
    __shared__ float red[2];
    const int b = blockIdx.x;
    const int t = threadIdx.x;
    for (int i = t; i < 1600; i += 256) {
        float s = b2[i];
        #pragma unroll 4
        for (int kz = 0; kz < 16; ++kz)
            s += part[((size_t)kz * NB + b) * 1600 + i];
        hrow[i] = s > 0.f ? s : 0.f;
    }
    __syncthreads();
    if (t < 41) {
        float acc = bc[t];
        for (int f = 0; f < 1600; ++f) acc += hrow[f] * Wc[f * 41 + t];
        lg[t] = acc;
    }
    __syncthreads();
    if (t == 0) {
        float mx = lg[0];
        for (int i = 1; i < 41; ++i) mx = fmaxf(mx, lg[i]);
        red[0] = mx;
    }
    __syncthreads();
    if (t < 41) lg[t] = expf(lg[t] - red[0]);
    __syncthreads();
    if (t == 0) {
        float sm = 0.f;
        for (int i = 0; i < 41; ++i) sm += lg[i];
        red[1] = 1.f / sm;
    }
    __syncthreads();
    if (t < 41) out[b * 41 + t] = lg[t] * red[1];
}

extern "C" void kernel_launch(void* const* d_in, const int* in_sizes, int n_in,
                              void* d_out, int out_size, void* d_ws, size_t ws_size,
                              hipStream_t stream)
{
    const float* x   = (const float*)d_in[0];    // [64,2048,128]
    const float* W0  = (const float*)d_in[1];    // [128,150]
    const float* U0  = (const float*)d_in[2];    // [50,150]
    const float* b0  = (const float*)d_in[3];    // [2,150]
    const float* Ws  = (const float*)d_in[4];    // [5,50,150]
    const float* Us  = (const float*)d_in[5];    // [5,50,150]
    const float* bs  = (const float*)d_in[6];    // [5,2,150]
    const float* W2  = (const float*)d_in[7];    // [1600,1600]
    const float* b2  = (const float*)d_in[8];    // [1600]
    const float* Wc  = (const float*)d_in[9];    // [1600,41]
    const float* bc  = (const float*)d_in[10];   // [41]

    float* xg   = (float*)d_ws;                       // MTOT*XGS f32  (79.7 MB)
    float* Xbuf = xg + (size_t)MTOT * XGS;            // MTOT*50 f32   (26.2 MB)
    float* part = xg;                                  // head partials reuse xg (6.6 MB)

    static const int rates[6] = {32, 64, 128, 256, 512, 1024};

    proj0_kernel<<<MTOT / 128, 256, 0, stream>>>(x, W0, b0, xg);
    gru_wave<2><<<rates[0] * NB / 8, 128, 0, stream>>>(
        xg, U0, b0, Xbuf, TTT / rates[0], rates[0] * NB);

    for (int l = 1; l < 6; ++l) {
        const float* Wl = Ws + (size_t)(l - 1) * HH * GG;
        const float* Ul = Us + (size_t)(l - 1) * HH * GG;
        const float* bl = bs + (size_t)(l - 1) * 2 * GG;
        projH_kernel<<<MTOT / 128, 256, 0, stream>>>(Xbuf, Wl, bl, xg);
        int rate = rates[l];
        int Nbatch = rate * NB;
        int dn = TTT / rate;
        gru_wave<4><<<Nbatch / 16, 256, 0, stream>>>(xg, Ul, bl, Xbuf, dn, Nbatch);
    }
    // head: split-K dense2 into partials (reuses xg), reduce+relu inside cls
    dense2_kernel<<<dim3(7, 8, 16), 256, 0, stream>>>(Xbuf, W2, part);
    cls_kernel<<<NB, 256, 0, stream>>>(part, b2, Wc, bc, (float*)d_out);
}

// Round 3
// 1173.863 us; speedup vs baseline: 4.9180x; 4.9180x over previous
//
#include <hip/hip_runtime.h>
#include <math.h>

// Dims (fixed by the problem)
#define HH   50          // hidden
#define GG   150         // 3H
#define XGS  152         // xg row stride (padded)
#define TTT  2048        // T
#define NB   64          // batch B
#define MTOT (TTT*NB)    // 131072 rows per layer
#define D0   128         // layer-0 input dim

static __device__ __forceinline__ float sigm(float x) {
    return 1.f / (1.f + __expf(-x));
}
static __device__ __forceinline__ float tanh_f(float x) {
    return 1.f - 2.f / (__expf(2.f * x) + 1.f);   // saturates correctly at +/-inf
}

static __device__ __forceinline__ void fma4(float4& a, float s, const float4& w) {
    a.x += s * w.x; a.y += s * w.y; a.z += s * w.z; a.w += s * w.w;
}

// ---------------- Layer-0 input projection: Xg = X0 @ W + bi ----------------
// Block = 128 rows x 32 cols; 256 threads = 32 rowq x 8 colq; ONE 4x4 tile
// per thread (16 acc floats -- no spill; round-2's 5-item version spilled to
// scratch: VGPR 256, 4.5 GB phantom traffic). Grid = 1024 row-tiles x 5
// col-tiles; the x5 re-read of x (64 MB) is L3-absorbed. K=128 staged in 4
// quarters. Per 4k: 8 ds_read_b128 -> 64 FMAs.
__global__ __launch_bounds__(256) void proj0_kernel(
    const float* __restrict__ x,              // [64,2048,128] f32
    const float* __restrict__ W,              // [128,150] f32
    const float* __restrict__ bias,           // [2,150] f32 (bi = bias[0])
    float* __restrict__ xg)                   // [MTOT,XGS] f32
{
    __shared__ float xs[128][36];             // k-quarter of x, stride 36 (18.4 KB)
    __shared__ float Wp[32][32];              // k-quarter of W cols for this tile (4 KB)
    const int tid  = threadIdx.x;
    const int m0   = blockIdx.x * 128;
    const int c0   = blockIdx.y * 32;         // col-tile base: 0,32,64,96,128
    const int rowq = tid >> 3;                // 0..31
    const int colq = tid & 7;                 // 0..7

    float4 acc[4];
    #pragma unroll
    for (int j = 0; j < 4; ++j) acc[j] = make_float4(0.f, 0.f, 0.f, 0.f);

    for (int q = 0; q < 4; ++q) {             // K quarters of 32
        if (q) __syncthreads();
        // stage x quarter: coalesced float4 global, conflict-balanced LDS writes
        for (int i = tid; i < 128 * 8; i += 256) {
            int r = i >> 3, k4 = (i & 7) * 4;
            int row = m0 + r, t = row >> 6, b = row & 63;
            *(float4*)&xs[r][k4] =
                *(const float4*)&x[((size_t)b * TTT + t) * D0 + q * 32 + k4];
        }
        // stage W quarter for this col-tile (zero-pad cols >= 150)
        for (int i = tid; i < 32 * 32; i += 256) {
            int k = i >> 5, c = i & 31, gc = c0 + c;
            Wp[k][c] = (gc < GG) ? W[(q * 32 + k) * GG + gc] : 0.f;
        }
        __syncthreads();
        const float* xr0 = xs[rowq * 4 + 0];
        const float* xr1 = xs[rowq * 4 + 1];
        const float* xr2 = xs[rowq * 4 + 2];
        const float* xr3 = xs[rowq * 4 + 3];
        for (int k = 0; k < 32; k += 4) {
            float4 w0 = *(const float4*)&Wp[k + 0][colq * 4];
            float4 w1 = *(const float4*)&Wp[k + 1][colq * 4];
            float4 w2 = *(const float4*)&Wp[k + 2][colq * 4];
            float4 w3 = *(const float4*)&Wp[k + 3][colq * 4];
            float4 x0 = *(const float4*)&xr0[k];
            float4 x1 = *(const float4*)&xr1[k];
            float4 x2 = *(const float4*)&xr2[k];
            float4 x3 = *(const float4*)&xr3[k];
            fma4(acc[0], x0.x, w0); fma4(acc[0], x0.y, w1);
            fma4(acc[0], x0.z, w2); fma4(acc[0], x0.w, w3);
            fma4(acc[1], x1.x, w0); fma4(acc[1], x1.y, w1);
            fma4(acc[1], x1.z, w2); fma4(acc[1], x1.w, w3);
            fma4(acc[2], x2.x, w0); fma4(acc[2], x2.y, w1);
            fma4(acc[2], x2.z, w2); fma4(acc[2], x2.w, w3);
            fma4(acc[3], x3.x, w0); fma4(acc[3], x3.y, w1);
            fma4(acc[3], x3.z, w2); fma4(acc[3], x3.w, w3);
        }
    }
    const int cc = c0 + colq * 4;
    if (cc <= XGS - 4) {                      // cc <= 148; cols 150/151 are unread pad
        float4 bv = *(const float4*)&bias[cc];
        #pragma unroll
        for (int j = 0; j < 4; ++j) {
            float4 o;
            o.x = acc[j].x + bv.x; o.y = acc[j].y + bv.y;
            o.z = acc[j].z + bv.z; o.w = acc[j].w + bv.w;
            *(float4*)&xg[(size_t)(m0 + rowq * 4 + j) * XGS + cc] = o;
        }
    }
}

// ---------------- Layers 1..5 input projection (K=50, padded to 52) ----------------
// Same geometry as proj0; K staged whole (xs[128][52] + Wp[52][32] = 33 KB).
__global__ __launch_bounds__(256) void projH_kernel(
    const float* __restrict__ Xin,            // [MTOT,50] f32 time-major
    const float* __restrict__ W,              // [50,150] f32
    const float* __restrict__ bias,           // [2,150] f32
    float* __restrict__ xg)                   // [MTOT,XGS] f32
{
    __shared__ float xs[128][52];             // 26.6 KB, k>=50 zero
    __shared__ float Wp[52][32];              // 6.7 KB, k>=50 / col>=150 zero
    const int tid  = threadIdx.x;
    const int m0   = blockIdx.x * 128;
    const int c0   = blockIdx.y * 32;
    const int rowq = tid >> 3;
    const int colq = tid & 7;

    for (int i = tid; i < 128 * 52; i += 256) {
        int r = i / 52, k = i - r * 52;
        xs[r][k] = (k < HH) ? Xin[(size_t)m0 * HH + r * HH + k] : 0.f;
    }
    for (int i = tid; i < 52 * 32; i += 256) {
        int k = i >> 5, c = i & 31, gc = c0 + c;
        Wp[k][c] = (k < HH && gc < GG) ? W[k * GG + gc] : 0.f;
    }
    __syncthreads();

    float4 acc[4];
    #pragma unroll
    for (int j = 0; j < 4; ++j) acc[j] = make_float4(0.f, 0.f, 0.f, 0.f);

    const float* xr0 = xs[rowq * 4 + 0];
    const float* xr1 = xs[rowq * 4 + 1];
    const float* xr2 = xs[rowq * 4 + 2];
    const float* xr3 = xs[rowq * 4 + 3];
    for (int k = 0; k < 52; k += 4) {         // 13 bundles; pads contribute 0
        float4 w0 = *(const float4*)&Wp[k + 0][colq * 4];
        float4 w1 = *(const float4*)&Wp[k + 1][colq * 4];
        float4 w2 = *(const float4*)&Wp[k + 2][colq * 4];
        float4 w3 = *(const float4*)&Wp[k + 3][colq * 4];
        float4 x0 = *(const float4*)&xr0[k];
        float4 x1 = *(const float4*)&xr1[k];
        float4 x2 = *(const float4*)&xr2[k];
        float4 x3 = *(const float4*)&xr3[k];
        fma4(acc[0], x0.x, w0); fma4(acc[0], x0.y, w1);
        fma4(acc[0], x0.z, w2); fma4(acc[0], x0.w, w3);
        fma4(acc[1], x1.x, w0); fma4(acc[1], x1.y, w1);
        fma4(acc[1], x1.z, w2); fma4(acc[1], x1.w, w3);
        fma4(acc[2], x2.x, w0); fma4(acc[2], x2.y, w1);
        fma4(acc[2], x2.z, w2); fma4(acc[2], x2.w, w3);
        fma4(acc[3], x3.x, w0); fma4(acc[3], x3.y, w1);
        fma4(acc[3], x3.z, w2); fma4(acc[3], x3.w, w3);
    }
    const int cc = c0 + colq * 4;
    if (cc <= XGS - 4) {
        float4 bv = *(const float4*)&bias[cc];
        #pragma unroll
        for (int j = 0; j < 4; ++j) {
            float4 o;
            o.x = acc[j].x + bv.x; o.y = acc[j].y + bv.y;
            o.z = acc[j].z + bv.z; o.w = acc[j].w + bv.w;
            *(float4*)&xg[(size_t)(m0 + rowq * 4 + j) * XGS + cc] = o;
        }
    }
}

// ---------------- GRU recurrence, barrier-free wave-autonomous (unchanged) ----------------
template<int WPB>
__global__ __launch_bounds__(WPB * 64) void gru_wave(
    const float* __restrict__ xg,             // [dn*Nbatch, XGS] f32 (includes bi)
    const float* __restrict__ U,              // [50,150] f32
    const float* __restrict__ bias,           // [2,150] f32 (br = bias+150)
    float* __restrict__ Xout,                 // [MTOT,50] f32 time-major
    int dn, int Nbatch)
{
    constexpr int R = 4 * WPB;                // rows per block
    __shared__ __align__(16) float Us[HH * XGS];      // 30.4 KB (cols padded to 152)
    __shared__ __align__(16) float brs[XGS];
    __shared__ __align__(16) float hsT[HH][R];        // transposed h, wave w owns cols 4w..4w+3
    __shared__ __align__(16) float rc[R][XGS];        // rec result, wave w owns rows 4w..4w+3

    const int tid  = threadIdx.x;
    const int wav  = tid >> 6;
    const int lane = tid & 63;

    for (int i = tid; i < HH * XGS; i += WPB * 64) {
        int c = i % XGS;
        Us[i] = (c < GG) ? U[(i / XGS) * GG + c] : 0.f;
    }
    for (int i = tid; i < XGS; i += WPB * 64) brs[i] = (i < GG) ? bias[GG + i] : 0.f;
    for (int i = tid; i < HH * R; i += WPB * 64) ((float*)hsT)[i] = 0.f;
    __syncthreads();                          // the only block-wide barrier

    const int cg = lane;                      // valid if < 38
    float4 brv = make_float4(0.f, 0.f, 0.f, 0.f);
    if (cg < 38) brv = *(const float4*)&brs[cg * 4];

    const int gr = lane >> 4;                 // 0..3 row within wave
    const int gk = lane & 15;
    const int nrow = blockIdx.x * R + wav * 4 + gr;
    const int jj = nrow >> 6, bb = nrow & 63;
    float hprev[4] = {0.f, 0.f, 0.f, 0.f};

    for (int s = 0; s < dn; ++s) {
        float pz[4], pr[4], ph[4];
        {
            const float* g = xg + ((size_t)s * Nbatch + nrow) * XGS;
            #pragma unroll
            for (int u = 0; u < 4; ++u) {
                int k = gk + 16 * u;
                if (k < HH) { pz[u] = g[k]; pr[u] = g[HH + k]; ph[u] = g[2 * HH + k]; }
            }
        }
        if (cg < 38) {
            float acc[4][4];
            #pragma unroll
            for (int j = 0; j < 4; ++j) {
                acc[j][0] = brv.x; acc[j][1] = brv.y; acc[j][2] = brv.z; acc[j][3] = brv.w;
            }
            #pragma unroll
            for (int k = 0; k < HH; ++k) {
                float4 w  = *(const float4*)&Us[k * XGS + cg * 4];
                float4 hv = *(const float4*)&hsT[k][wav * 4];
                float hj[4] = {hv.x, hv.y, hv.z, hv.w};
                float wc[4] = {w.x, w.y, w.z, w.w};
                #pragma unroll
                for (int j = 0; j < 4; ++j)
                    #pragma unroll
                    for (int c = 0; c < 4; ++c) acc[j][c] += hj[j] * wc[c];
            }
            #pragma unroll
            for (int j = 0; j < 4; ++j)
                *(float4*)&rc[wav * 4 + j][cg * 4] = *(const float4*)&acc[j][0];
        }
        const float* rcrow = rc[wav * 4 + gr];
        #pragma unroll
        for (int u = 0; u < 4; ++u) {
            int k = gk + 16 * u;
            if (k < HH) {
                float rcz = rcrow[k];
                float rcr = rcrow[HH + k];
                float rch = rcrow[2 * HH + k];
                float z  = sigm(pz[u] + rcz);
                float rr = sigm(pr[u] + rcr);
                float hh = tanh_f(ph[u] + rr * rch);
                float hn = z * hprev[u] + (1.f - z) * hh;
                hprev[u] = hn;
                hsT[k][wav * 4 + gr] = hn;
                Xout[((size_t)(jj * dn + s) * NB + bb) * HH + k] = hn;
            }
        }
    }
}

// ---------------- Head: split-K partial GEMM (no bias/relu here) ----------------
// grid (7, 8, 16): 896 blocks. part[kz][64][1600] partial sums over 100-feature
// slices. Deterministic (no atomics); reduction folded into cls_kernel.
__global__ __launch_bounds__(256) void dense2_kernel(
    const float* __restrict__ X,              // [MTOT,50] f32 final layer (time-major)
    const float* __restrict__ W2,             // [1600,1600] f32
    float* __restrict__ part)                 // [16,64,1600] f32 partials
{
    __shared__ float fs[8][100];              // 3.2 KB
    const int tid = threadIdx.x;
    const int c  = blockIdx.x * 256 + tid;
    const int r0 = blockIdx.y * 8;
    const int kz = blockIdx.z;
    for (int i = tid; i < 8 * 100; i += 256) {
        int r = i / 100, fl = i - r * 100;
        int f = kz * 100 + fl, j = f / HH, k = f - j * HH;
        fs[r][fl] = X[((size_t)(TTT - 32 + j) * NB + (r0 + r)) * HH + k];
    }
    __syncthreads();
    if (c < 1600) {
        float a[8] = {0, 0, 0, 0, 0, 0, 0, 0};
        const float* w = W2 + (size_t)kz * 100 * 1600 + c;
        for (int fl = 0; fl < 100; ++fl) {
            float wv = w[(size_t)fl * 1600];
            #pragma unroll
            for (int r = 0; r < 8; ++r) a[r] += fs[r][fl] * wv;
        }
        #pragma unroll
        for (int r = 0; r < 8; ++r)
            part[((size_t)kz * NB + r0 + r) * 1600 + c] = a[r];
    }
}

// ---------------- Classifier: sum partials + bias + relu, then softmax ----------------
__global__ __launch_bounds__(256) void cls_kernel(
    const float* __restrict__ part,           // [16,64,1600] f32 partials
    const float* __restrict__ b2,             // [1600] f32
    const float* __restrict__ Wc,             // [1600,41] f32
    const float* __restrict__ bc,             // [41] f32
    float* __restrict__ out)                  // [64,41] f32
{
    __shared__ float hrow[1600];
    __shared__ float lg[41];
    __shared__ float red[2];
    const int b = blockIdx.x;
    const int t = threadIdx.x;
    for (int i = t; i < 1600; i += 256) {
        float s = b2[i];
        #pragma unroll 4
        for (int kz = 0; kz < 16; ++kz)
            s += part[((size_t)kz * NB + b) * 1600 + i];
        hrow[i] = s > 0.f ? s : 0.f;
    }
    __syncthreads();
    if (t < 41) {
        float acc = bc[t];
        for (int f = 0; f < 1600; ++f) acc += hrow[f] * Wc[f * 41 + t];
        lg[t] = acc;
    }
    __syncthreads();
    if (t == 0) {
        float mx = lg[0];
        for (int i = 1; i < 41; ++i) mx = fmaxf(mx, lg[i]);
        red[0] = mx;
    }
    __syncthreads();
    if (t < 41) lg[t] = expf(lg[t] - red[0]);
    __syncthreads();
    if (t == 0) {
        float sm = 0.f;
        for (int i = 0; i < 41; ++i) sm += lg[i];
        red[1] = 1.f / sm;
    }
    __syncthreads();
    if (t < 41) out[b * 41 + t] = lg[t] * red[1];
}

extern "C" void kernel_launch(void* const* d_in, const int* in_sizes, int n_in,
                              void* d_out, int out_size, void* d_ws, size_t ws_size,
                              hipStream_t stream)
{
    const float* x   = (const float*)d_in[0];    // [64,2048,128]
    const float* W0  = (const float*)d_in[1];    // [128,150]
    const float* U0  = (const float*)d_in[2];    // [50,150]
    const float* b0  = (const float*)d_in[3];    // [2,150]
    const float* Ws  = (const float*)d_in[4];    // [5,50,150]
    const float* Us  = (const float*)d_in[5];    // [5,50,150]
    const float* bs  = (const float*)d_in[6];    // [5,2,150]
    const float* W2  = (const float*)d_in[7];    // [1600,1600]
    const float* b2  = (const float*)d_in[8];    // [1600]
    const float* Wc  = (const float*)d_in[9];    // [1600,41]
    const float* bc  = (const float*)d_in[10];   // [41]

    float* xg   = (float*)d_ws;                       // MTOT*XGS f32  (79.7 MB)
    float* Xbuf = xg + (size_t)MTOT * XGS;            // MTOT*50 f32   (26.2 MB)
    float* part = xg;                                  // head partials reuse xg (6.6 MB)

    static const int rates[6] = {32, 64, 128, 256, 512, 1024};

    proj0_kernel<<<dim3(MTOT / 128, 5), 256, 0, stream>>>(x, W0, b0, xg);
    gru_wave<2><<<rates[0] * NB / 8, 128, 0, stream>>>(
        xg, U0, b0, Xbuf, TTT / rates[0], rates[0] * NB);

    for (int l = 1; l < 6; ++l) {
        const float* Wl = Ws + (size_t)(l - 1) * HH * GG;
        const float* Ul = Us + (size_t)(l - 1) * HH * GG;
        const float* bl = bs + (size_t)(l - 1) * 2 * GG;
        projH_kernel<<<dim3(MTOT / 128, 5), 256, 0, stream>>>(Xbuf, Wl, bl, xg);
        int rate = rates[l];
        int Nbatch = rate * NB;
        int dn = TTT / rate;
        gru_wave<4><<<Nbatch / 16, 256, 0, stream>>>(xg, Ul, bl, Xbuf, dn, Nbatch);
    }
    // head: split-K dense2 into partials (reuses xg), reduce+relu inside cls
    dense2_kernel<<<dim3(7, 8, 16), 256, 0, stream>>>(Xbuf, W2, part);
    cls_kernel<<<NB, 256, 0, stream>>>(part, b2, Wc, bc, (float*)d_out);
}

// Round 4
// 1147.163 us; speedup vs baseline: 5.0325x; 1.0233x over previous
//
#include <hip/hip_runtime.h>
#include <math.h>

// Dims (fixed by the problem)
#define HH   50          // hidden
#define GG   150         // 3H
#define XGS  152         // xg row stride (padded)
#define TTT  2048        // T
#define NB   64          // batch B
#define MTOT (TTT*NB)    // 131072 rows per layer
#define D0   128         // layer-0 input dim

static __device__ __forceinline__ float sigm(float x) {
    return 1.f / (1.f + __expf(-x));
}
static __device__ __forceinline__ float tanh_f(float x) {
    return 1.f - 2.f / (__expf(2.f * x) + 1.f);   // saturates correctly at +/-inf
}

static __device__ __forceinline__ void fma4(float4& a, float s, const float4& w) {
    a.x += s * w.x; a.y += s * w.y; a.z += s * w.z; a.w += s * w.w;
}

// ---------------- Layer-0 input projection: Xg = X0 @ W + bi ----------------
// Block = 128 rows x 32 cols; 256 threads = 32 rowq x 8 colq; ONE 4x4 tile
// per thread (16 acc floats -- no spill). Grid = 1024 row-tiles x 5 col-tiles;
// the x5 re-read of x (64 MB) is L3-absorbed. K=128 staged in 4 quarters.
__global__ __launch_bounds__(256) void proj0_kernel(
    const float* __restrict__ x,              // [64,2048,128] f32
    const float* __restrict__ W,              // [128,150] f32
    const float* __restrict__ bias,           // [2,150] f32 (bi = bias[0])
    float* __restrict__ xg)                   // [MTOT,XGS] f32
{
    __shared__ float xs[128][36];             // k-quarter of x, stride 36 (18.4 KB)
    __shared__ float Wp[32][32];              // k-quarter of W cols for this tile (4 KB)
    const int tid  = threadIdx.x;
    const int m0   = blockIdx.x * 128;
    const int c0   = blockIdx.y * 32;         // col-tile base: 0,32,64,96,128
    const int rowq = tid >> 3;                // 0..31
    const int colq = tid & 7;                 // 0..7

    float4 acc[4];
    #pragma unroll
    for (int j = 0; j < 4; ++j) acc[j] = make_float4(0.f, 0.f, 0.f, 0.f);

    for (int q = 0; q < 4; ++q) {             // K quarters of 32
        if (q) __syncthreads();
        for (int i = tid; i < 128 * 8; i += 256) {
            int r = i >> 3, k4 = (i & 7) * 4;
            int row = m0 + r, t = row >> 6, b = row & 63;
            *(float4*)&xs[r][k4] =
                *(const float4*)&x[((size_t)b * TTT + t) * D0 + q * 32 + k4];
        }
        for (int i = tid; i < 32 * 32; i += 256) {
            int k = i >> 5, c = i & 31, gc = c0 + c;
            Wp[k][c] = (gc < GG) ? W[(q * 32 + k) * GG + gc] : 0.f;
        }
        __syncthreads();
        const float* xr0 = xs[rowq * 4 + 0];
        const float* xr1 = xs[rowq * 4 + 1];
        const float* xr2 = xs[rowq * 4 + 2];
        const float* xr3 = xs[rowq * 4 + 3];
        for (int k = 0; k < 32; k += 4) {
            float4 w0 = *(const float4*)&Wp[k + 0][colq * 4];
            float4 w1 = *(const float4*)&Wp[k + 1][colq * 4];
            float4 w2 = *(const float4*)&Wp[k + 2][colq * 4];
            float4 w3 = *(const float4*)&Wp[k + 3][colq * 4];
            float4 x0 = *(const float4*)&xr0[k];
            float4 x1 = *(const float4*)&xr1[k];
            float4 x2 = *(const float4*)&xr2[k];
            float4 x3 = *(const float4*)&xr3[k];
            fma4(acc[0], x0.x, w0); fma4(acc[0], x0.y, w1);
            fma4(acc[0], x0.z, w2); fma4(acc[0], x0.w, w3);
            fma4(acc[1], x1.x, w0); fma4(acc[1], x1.y, w1);
            fma4(acc[1], x1.z, w2); fma4(acc[1], x1.w, w3);
            fma4(acc[2], x2.x, w0); fma4(acc[2], x2.y, w1);
            fma4(acc[2], x2.z, w2); fma4(acc[2], x2.w, w3);
            fma4(acc[3], x3.x, w0); fma4(acc[3], x3.y, w1);
            fma4(acc[3], x3.z, w2); fma4(acc[3], x3.w, w3);
        }
    }
    const int cc = c0 + colq * 4;
    if (cc <= XGS - 4) {                      // cc <= 148; cols 150/151 unread pad
        float4 bv = *(const float4*)&bias[cc];
        #pragma unroll
        for (int j = 0; j < 4; ++j) {
            float4 o;
            o.x = acc[j].x + bv.x; o.y = acc[j].y + bv.y;
            o.z = acc[j].z + bv.z; o.w = acc[j].w + bv.w;
            *(float4*)&xg[(size_t)(m0 + rowq * 4 + j) * XGS + cc] = o;
        }
    }
}

// ---------------- Layers 1..5 input projection (K=50, padded to 52) ----------------
__global__ __launch_bounds__(256) void projH_kernel(
    const float* __restrict__ Xin,            // [MTOT,50] f32 time-major
    const float* __restrict__ W,              // [50,150] f32
    const float* __restrict__ bias,           // [2,150] f32
    float* __restrict__ xg)                   // [MTOT,XGS] f32
{
    __shared__ float xs[128][52];             // 26.6 KB, k>=50 zero
    __shared__ float Wp[52][32];              // 6.7 KB, k>=50 / col>=150 zero
    const int tid  = threadIdx.x;
    const int m0   = blockIdx.x * 128;
    const int c0   = blockIdx.y * 32;
    const int rowq = tid >> 3;
    const int colq = tid & 7;

    for (int i = tid; i < 128 * 52; i += 256) {
        int r = i / 52, k = i - r * 52;
        xs[r][k] = (k < HH) ? Xin[(size_t)m0 * HH + r * HH + k] : 0.f;
    }
    for (int i = tid; i < 52 * 32; i += 256) {
        int k = i >> 5, c = i & 31, gc = c0 + c;
        Wp[k][c] = (k < HH && gc < GG) ? W[k * GG + gc] : 0.f;
    }
    __syncthreads();

    float4 acc[4];
    #pragma unroll
    for (int j = 0; j < 4; ++j) acc[j] = make_float4(0.f, 0.f, 0.f, 0.f);

    const float* xr0 = xs[rowq * 4 + 0];
    const float* xr1 = xs[rowq * 4 + 1];
    const float* xr2 = xs[rowq * 4 + 2];
    const float* xr3 = xs[rowq * 4 + 3];
    for (int k = 0; k < 52; k += 4) {         // 13 bundles; pads contribute 0
        float4 w0 = *(const float4*)&Wp[k + 0][colq * 4];
        float4 w1 = *(const float4*)&Wp[k + 1][colq * 4];
        float4 w2 = *(const float4*)&Wp[k + 2][colq * 4];
        float4 w3 = *(const float4*)&Wp[k + 3][colq * 4];
        float4 x0 = *(const float4*)&xr0[k];
        float4 x1 = *(const float4*)&xr1[k];
        float4 x2 = *(const float4*)&xr2[k];
        float4 x3 = *(const float4*)&xr3[k];
        fma4(acc[0], x0.x, w0); fma4(acc[0], x0.y, w1);
        fma4(acc[0], x0.z, w2); fma4(acc[0], x0.w, w3);
        fma4(acc[1], x1.x, w0); fma4(acc[1], x1.y, w1);
        fma4(acc[1], x1.z, w2); fma4(acc[1], x1.w, w3);
        fma4(acc[2], x2.x, w0); fma4(acc[2], x2.y, w1);
        fma4(acc[2], x2.z, w2); fma4(acc[2], x2.w, w3);
        fma4(acc[3], x3.x, w0); fma4(acc[3], x3.y, w1);
        fma4(acc[3], x3.z, w2); fma4(acc[3], x3.w, w3);
    }
    const int cc = c0 + colq * 4;
    if (cc <= XGS - 4) {
        float4 bv = *(const float4*)&bias[cc];
        #pragma unroll
        for (int j = 0; j < 4; ++j) {
            float4 o;
            o.x = acc[j].x + bv.x; o.y = acc[j].y + bv.y;
            o.z = acc[j].z + bv.z; o.w = acc[j].w + bv.w;
            *(float4*)&xg[(size_t)(m0 + rowq * 4 + j) * XGS + cc] = o;
        }
    }
}

// ---------------- GRU recurrence: lane = hidden unit, rec stays in registers ----------------
// Lane c (c<50) owns hidden unit c for this wave's RPW rows. Per step, per k:
// one ds_read_b128 of Ut[k][c][{z,r,h,0}] + one b64/b128 broadcast of
// hsT[k][rows] -> 3*RPW FMAs. Gate pre-activations never leave registers
// (old rc LDS round-trip eliminated). Grid-stride over row-groups so U is
// staged once per block (key for layers with dn=2..8). Barrier-free step
// loop: each wave touches only its own hsT columns; in-wave DS ordering
// makes write->read safe.
template<int WPB, int RPW>
__global__ __launch_bounds__(WPB * 64) void gru_wave(
    const float* __restrict__ xg,             // [dn*Nbatch, XGS] f32 (includes bi)
    const float* __restrict__ U,              // [50,150] f32
    const float* __restrict__ bias,           // [2,150] f32 (br = bias+150)
    float* __restrict__ Xout,                 // [MTOT,50] f32 time-major
    int dn, int Nbatch, int ngroups)
{
    constexpr int R = WPB * RPW;              // rows per block per group
    __shared__ __align__(16) float Ut[HH][HH][4];   // [k][c][{z,r,h,0}] 40 KB
    __shared__ __align__(16) float hsT[HH][R];      // transposed h, wave w owns cols w*RPW..

    const int tid  = threadIdx.x;
    const int wav  = tid >> 6;
    const int lane = tid & 63;

    for (int i = tid; i < HH * HH; i += WPB * 64)
        Ut[i / HH][i - (i / HH) * HH][3] = 0.f;
    for (int i = tid; i < HH * GG; i += WPB * 64) {
        int k = i / GG, cc = i - k * GG;
        Ut[k][cc % HH][cc / HH] = U[i];       // col layout: [z|r|h] blocks of 50
    }
    __syncthreads();                          // the only block-wide barrier

    const int c = lane;
    if (c >= HH) return;                      // lanes 50..63 idle (no barriers follow)

    const float bz = bias[GG + c];
    const float brr = bias[GG + HH + c];
    const float bh = bias[GG + 2 * HH + c];

    for (int grp = blockIdx.x; grp < ngroups; grp += gridDim.x) {
        const int row0 = grp * R + wav * RPW;
        float hprev[RPW];
        #pragma unroll
        for (int j = 0; j < RPW; ++j) {
            hprev[j] = 0.f;
            hsT[c][wav * RPW + j] = 0.f;
        }
        size_t obase[RPW];
        #pragma unroll
        for (int j = 0; j < RPW; ++j) {
            int nr = row0 + j;
            obase[j] = ((size_t)((nr >> 6) * dn) * NB + (nr & 63)) * HH + c;
        }
        const float* gb = xg + (size_t)row0 * XGS;

        for (int s = 0; s < dn; ++s) {
            // prefetch this step's gate inputs (hidden-unit c only; coalesced)
            float px[RPW], pr[RPW], ph[RPW];
            #pragma unroll
            for (int j = 0; j < RPW; ++j) {
                const float* g = gb + ((size_t)s * Nbatch + j) * XGS;
                px[j] = g[c]; pr[j] = g[HH + c]; ph[j] = g[2 * HH + c];
            }
            // rec = h @ U + br, only cols {c, 50+c, 100+c} -- in registers
            float az[RPW], ar[RPW], ah[RPW];
            #pragma unroll
            for (int j = 0; j < RPW; ++j) { az[j] = bz; ar[j] = brr; ah[j] = bh; }
            #pragma unroll
            for (int k = 0; k < HH; ++k) {
                float4 w = *(const float4*)&Ut[k][c][0];
                float hv[4];
                if (RPW == 4) {
                    float4 t = *(const float4*)&hsT[k][wav * RPW];
                    hv[0] = t.x; hv[1] = t.y; hv[2] = t.z; hv[3] = t.w;
                } else {
                    float2 t = *(const float2*)&hsT[k][wav * RPW];
                    hv[0] = t.x; hv[1] = t.y; hv[2] = 0.f; hv[3] = 0.f;
                }
                #pragma unroll
                for (int j = 0; j < RPW; ++j) {
                    az[j] += hv[j] * w.x;
                    ar[j] += hv[j] * w.y;
                    ah[j] += hv[j] * w.z;
                }
            }
            // gates + state update, all in registers
            #pragma unroll
            for (int j = 0; j < RPW; ++j) {
                float z  = sigm(px[j] + az[j]);
                float r  = sigm(pr[j] + ar[j]);
                float hh = tanh_f(ph[j] + r * ah[j]);
                float hn = z * hprev[j] + (1.f - z) * hh;
                hprev[j] = hn;
                hsT[c][wav * RPW + j] = hn;
                Xout[obase[j] + (size_t)s * NB * HH] = hn;
            }
        }
    }
}

// ---------------- Head: split-K partial GEMM (no bias/relu here) ----------------
__global__ __launch_bounds__(256) void dense2_kernel(
    const float* __restrict__ X,              // [MTOT,50] f32 final layer (time-major)
    const float* __restrict__ W2,             // [1600,1600] f32
    float* __restrict__ part)                 // [16,64,1600] f32 partials
{
    __shared__ float fs[8][100];              // 3.2 KB
    const int tid = threadIdx.x;
    const int c  = blockIdx.x * 256 + tid;
    const int r0 = blockIdx.y * 8;
    const int kz = blockIdx.z;
    for (int i = tid; i < 8 * 100; i += 256) {
        int r = i / 100, fl = i - r * 100;
        int f = kz * 100 + fl, j = f / HH, k = f - j * HH;
        fs[r][fl] = X[((size_t)(TTT - 32 + j) * NB + (r0 + r)) * HH + k];
    }
    __syncthreads();
    if (c < 1600) {
        float a[8] = {0, 0, 0, 0, 0, 0, 0, 0};
        const float* w = W2 + (size_t)kz * 100 * 1600 + c;
        for (int fl = 0; fl < 100; ++fl) {
            float wv = w[(size_t)fl * 1600];
            #pragma unroll
            for (int r = 0; r < 8; ++r) a[r] += fs[r][fl] * wv;
        }
        #pragma unroll
        for (int r = 0; r < 8; ++r)
            part[((size_t)kz * NB + r0 + r) * 1600 + c] = a[r];
    }
}

// ---------------- Classifier: sum partials + bias + relu, then softmax ----------------
__global__ __launch_bounds__(256) void cls_kernel(
    const float* __restrict__ part,           // [16,64,1600] f32 partials
    const float* __restrict__ b2,             // [1600] f32
    const float* __restrict__ Wc,             // [1600,41] f32
    const float* __restrict__ bc,             // [41] f32
    float* __restrict__ out)                  // [64,41] f32
{
    __shared__ float hrow[1600];
    __shared__ float lg[41];
    __shared__ float red[2];
    const int b = blockIdx.x;
    const int t = threadIdx.x;
    for (int i = t; i < 1600; i += 256) {
        float s = b2[i];
        #pragma unroll 4
        for (int kz = 0; kz < 16; ++kz)
            s += part[((size_t)kz * NB + b) * 1600 + i];
        hrow[i] = s > 0.f ? s : 0.f;
    }
    __syncthreads();
    if (t < 41) {
        float acc = bc[t];
        for (int f = 0; f < 1600; ++f) acc += hrow[f] * Wc[f * 41 + t];
        lg[t] = acc;
    }
    __syncthreads();
    if (t == 0) {
        float mx = lg[0];
        for (int i = 1; i < 41; ++i) mx = fmaxf(mx, lg[i]);
        red[0] = mx;
    }
    __syncthreads();
    if (t < 41) lg[t] = expf(lg[t] - red[0]);
    __syncthreads();
    if (t == 0) {
        float sm = 0.f;
        for (int i = 0; i < 41; ++i) sm += lg[i];
        red[1] = 1.f / sm;
    }
    __syncthreads();
    if (t < 41) out[b * 41 + t] = lg[t] * red[1];
}

extern "C" void kernel_launch(void* const* d_in, const int* in_sizes, int n_in,
                              void* d_out, int out_size, void* d_ws, size_t ws_size,
                              hipStream_t stream)
{
    const float* x   = (const float*)d_in[0];    // [64,2048,128]
    const float* W0  = (const float*)d_in[1];    // [128,150]
    const float* U0  = (const float*)d_in[2];    // [50,150]
    const float* b0  = (const float*)d_in[3];    // [2,150]
    const float* Ws  = (const float*)d_in[4];    // [5,50,150]
    const float* Us  = (const float*)d_in[5];    // [5,50,150]
    const float* bs  = (const float*)d_in[6];    // [5,2,150]
    const float* W2  = (const float*)d_in[7];    // [1600,1600]
    const float* b2  = (const float*)d_in[8];    // [1600]
    const float* Wc  = (const float*)d_in[9];    // [1600,41]
    const float* bc  = (const float*)d_in[10];   // [41]

    float* xg   = (float*)d_ws;                       // MTOT*XGS f32  (79.7 MB)
    float* Xbuf = xg + (size_t)MTOT * XGS;            // MTOT*50 f32   (26.2 MB)
    float* part = xg;                                  // head partials reuse xg (6.6 MB)

    static const int rates[6] = {32, 64, 128, 256, 512, 1024};

    proj0_kernel<<<dim3(MTOT / 128, 5), 256, 0, stream>>>(x, W0, b0, xg);
    {
        int dn = TTT / rates[0], Nbatch = rates[0] * NB;   // 64, 2048
        int ngroups = Nbatch / 8;                          // R=8 for <4,2>
        int grid = ngroups < 768 ? ngroups : 768;
        gru_wave<4, 2><<<grid, 256, 0, stream>>>(xg, U0, b0, Xbuf, dn, Nbatch, ngroups);
    }

    for (int l = 1; l < 6; ++l) {
        const float* Wl = Ws + (size_t)(l - 1) * HH * GG;
        const float* Ul = Us + (size_t)(l - 1) * HH * GG;
        const float* bl = bs + (size_t)(l - 1) * 2 * GG;
        projH_kernel<<<dim3(MTOT / 128, 5), 256, 0, stream>>>(Xbuf, Wl, bl, xg);
        int rate = rates[l];
        int Nbatch = rate * NB;
        int dn = TTT / rate;
        if (l == 1) {
            int ngroups = Nbatch / 8;                      // R=8, more waves for dn=32
            int grid = ngroups < 768 ? ngroups : 768;
            gru_wave<4, 2><<<grid, 256, 0, stream>>>(xg, Ul, bl, Xbuf, dn, Nbatch, ngroups);
        } else {
            int ngroups = Nbatch / 16;                     // R=16, issue-efficient
            int grid = ngroups < 768 ? ngroups : 768;
            gru_wave<4, 4><<<grid, 256, 0, stream>>>(xg, Ul, bl, Xbuf, dn, Nbatch, ngroups);
        }
    }
    // head: split-K dense2 into partials (reuses xg), reduce+relu inside cls
    dense2_kernel<<<dim3(7, 8, 16), 256, 0, stream>>>(Xbuf, W2, part);
    cls_kernel<<<NB, 256, 0, stream>>>(part, b2, Wc, bc, (float*)d_out);
}

// Round 5
// 1111.968 us; speedup vs baseline: 5.1918x; 1.0317x over previous
//
#include <hip/hip_runtime.h>
#include <math.h>

// Dims (fixed by the problem)
#define HH   50          // hidden
#define GG   150         // 3H
#define XGS  152         // xg row stride (padded)
#define TTT  2048        // T
#define NB   64          // batch B
#define MTOT (TTT*NB)    // 131072 rows per layer
#define D0   128         // layer-0 input dim

static __device__ __forceinline__ float sigm(float x) {
    return 1.f / (1.f + __expf(-x));
}
static __device__ __forceinline__ float tanh_f(float x) {
    return 1.f - 2.f / (__expf(2.f * x) + 1.f);   // saturates correctly at +/-inf
}

static __device__ __forceinline__ void fma4(float4& a, float s, const float4& w) {
    a.x += s * w.x; a.y += s * w.y; a.z += s * w.z; a.w += s * w.w;
}

static __device__ __forceinline__ float bcast(float v, int k) {
    // wave-uniform broadcast of lane k's value; k is compile-time after unroll
    return __uint_as_float(__builtin_amdgcn_readlane(__float_as_uint(v), k));
}

// ---------------- Layer-0 input projection: Xg = X0 @ W + bi ----------------
// Block = 128 rows x 32 cols; 256 threads = 32 rowq x 8 colq; ONE 4x4 tile
// per thread (16 acc floats -- no spill). Grid = 1024 row-tiles x 5 col-tiles;
// the x5 re-read of x (64 MB) is L3-absorbed. K=128 staged in 4 quarters.
__global__ __launch_bounds__(256) void proj0_kernel(
    const float* __restrict__ x,              // [64,2048,128] f32
    const float* __restrict__ W,              // [128,150] f32
    const float* __restrict__ bias,           // [2,150] f32 (bi = bias[0])
    float* __restrict__ xg)                   // [MTOT,XGS] f32
{
    __shared__ float xs[128][36];             // k-quarter of x, stride 36 (18.4 KB)
    __shared__ float Wp[32][32];              // k-quarter of W cols for this tile (4 KB)
    const int tid  = threadIdx.x;
    const int m0   = blockIdx.x * 128;
    const int c0   = blockIdx.y * 32;         // col-tile base: 0,32,64,96,128
    const int rowq = tid >> 3;                // 0..31
    const int colq = tid & 7;                 // 0..7

    float4 acc[4];
    #pragma unroll
    for (int j = 0; j < 4; ++j) acc[j] = make_float4(0.f, 0.f, 0.f, 0.f);

    for (int q = 0; q < 4; ++q) {             // K quarters of 32
        if (q) __syncthreads();
        for (int i = tid; i < 128 * 8; i += 256) {
            int r = i >> 3, k4 = (i & 7) * 4;
            int row = m0 + r, t = row >> 6, b = row & 63;
            *(float4*)&xs[r][k4] =
                *(const float4*)&x[((size_t)b * TTT + t) * D0 + q * 32 + k4];
        }
        for (int i = tid; i < 32 * 32; i += 256) {
            int k = i >> 5, c = i & 31, gc = c0 + c;
            Wp[k][c] = (gc < GG) ? W[(q * 32 + k) * GG + gc] : 0.f;
        }
        __syncthreads();
        const float* xr0 = xs[rowq * 4 + 0];
        const float* xr1 = xs[rowq * 4 + 1];
        const float* xr2 = xs[rowq * 4 + 2];
        const float* xr3 = xs[rowq * 4 + 3];
        for (int k = 0; k < 32; k += 4) {
            float4 w0 = *(const float4*)&Wp[k + 0][colq * 4];
            float4 w1 = *(const float4*)&Wp[k + 1][colq * 4];
            float4 w2 = *(const float4*)&Wp[k + 2][colq * 4];
            float4 w3 = *(const float4*)&Wp[k + 3][colq * 4];
            float4 x0 = *(const float4*)&xr0[k];
            float4 x1 = *(const float4*)&xr1[k];
            float4 x2 = *(const float4*)&xr2[k];
            float4 x3 = *(const float4*)&xr3[k];
            fma4(acc[0], x0.x, w0); fma4(acc[0], x0.y, w1);
            fma4(acc[0], x0.z, w2); fma4(acc[0], x0.w, w3);
            fma4(acc[1], x1.x, w0); fma4(acc[1], x1.y, w1);
            fma4(acc[1], x1.z, w2); fma4(acc[1], x1.w, w3);
            fma4(acc[2], x2.x, w0); fma4(acc[2], x2.y, w1);
            fma4(acc[2], x2.z, w2); fma4(acc[2], x2.w, w3);
            fma4(acc[3], x3.x, w0); fma4(acc[3], x3.y, w1);
            fma4(acc[3], x3.z, w2); fma4(acc[3], x3.w, w3);
        }
    }
    const int cc = c0 + colq * 4;
    if (cc <= XGS - 4) {                      // cc <= 148; cols 150/151 unread pad
        float4 bv = *(const float4*)&bias[cc];
        #pragma unroll
        for (int j = 0; j < 4; ++j) {
            float4 o;
            o.x = acc[j].x + bv.x; o.y = acc[j].y + bv.y;
            o.z = acc[j].z + bv.z; o.w = acc[j].w + bv.w;
            *(float4*)&xg[(size_t)(m0 + rowq * 4 + j) * XGS + cc] = o;
        }
    }
}

// ---------------- Layers 1..5 input projection (K=50, padded to 52) ----------------
__global__ __launch_bounds__(256) void projH_kernel(
    const float* __restrict__ Xin,            // [MTOT,50] f32 time-major
    const float* __restrict__ W,              // [50,150] f32
    const float* __restrict__ bias,           // [2,150] f32
    float* __restrict__ xg)                   // [MTOT,XGS] f32
{
    __shared__ float xs[128][52];             // 26.6 KB, k>=50 zero
    __shared__ float Wp[52][32];              // 6.7 KB, k>=50 / col>=150 zero
    const int tid  = threadIdx.x;
    const int m0   = blockIdx.x * 128;
    const int c0   = blockIdx.y * 32;
    const int rowq = tid >> 3;
    const int colq = tid & 7;

    for (int i = tid; i < 128 * 52; i += 256) {
        int r = i / 52, k = i - r * 52;
        xs[r][k] = (k < HH) ? Xin[(size_t)m0 * HH + r * HH + k] : 0.f;
    }
    for (int i = tid; i < 52 * 32; i += 256) {
        int k = i >> 5, c = i & 31, gc = c0 + c;
        Wp[k][c] = (k < HH && gc < GG) ? W[k * GG + gc] : 0.f;
    }
    __syncthreads();

    float4 acc[4];
    #pragma unroll
    for (int j = 0; j < 4; ++j) acc[j] = make_float4(0.f, 0.f, 0.f, 0.f);

    const float* xr0 = xs[rowq * 4 + 0];
    const float* xr1 = xs[rowq * 4 + 1];
    const float* xr2 = xs[rowq * 4 + 2];
    const float* xr3 = xs[rowq * 4 + 3];
    for (int k = 0; k < 52; k += 4) {         // 13 bundles; pads contribute 0
        float4 w0 = *(const float4*)&Wp[k + 0][colq * 4];
        float4 w1 = *(const float4*)&Wp[k + 1][colq * 4];
        float4 w2 = *(const float4*)&Wp[k + 2][colq * 4];
        float4 w3 = *(const float4*)&Wp[k + 3][colq * 4];
        float4 x0 = *(const float4*)&xr0[k];
        float4 x1 = *(const float4*)&xr1[k];
        float4 x2 = *(const float4*)&xr2[k];
        float4 x3 = *(const float4*)&xr3[k];
        fma4(acc[0], x0.x, w0); fma4(acc[0], x0.y, w1);
        fma4(acc[0], x0.z, w2); fma4(acc[0], x0.w, w3);
        fma4(acc[1], x1.x, w0); fma4(acc[1], x1.y, w1);
        fma4(acc[1], x1.z, w2); fma4(acc[1], x1.w, w3);
        fma4(acc[2], x2.x, w0); fma4(acc[2], x2.y, w1);
        fma4(acc[2], x2.z, w2); fma4(acc[2], x2.w, w3);
        fma4(acc[3], x3.x, w0); fma4(acc[3], x3.y, w1);
        fma4(acc[3], x3.z, w2); fma4(acc[3], x3.w, w3);
    }
    const int cc = c0 + colq * 4;
    if (cc <= XGS - 4) {
        float4 bv = *(const float4*)&bias[cc];
        #pragma unroll
        for (int j = 0; j < 4; ++j) {
            float4 o;
            o.x = acc[j].x + bv.x; o.y = acc[j].y + bv.y;
            o.z = acc[j].z + bv.z; o.w = acc[j].w + bv.w;
            *(float4*)&xg[(size_t)(m0 + rowq * 4 + j) * XGS + cc] = o;
        }
    }
}

// ---------------- GRU recurrence: h in registers, readlane broadcast ----------------
// Lane c = hidden unit c; h_c lives in lane c's register. Rec matvec needs
// h_k broadcast -> v_readlane (VALU, no lgkmcnt). Step loop has ZERO LDS
// writes and zero LDS dependencies: Ut reads are loop-invariant addresses
// (prefetchable), Ut[k][c][.] is consecutive-16B-per-lane = conflict-free
// b128. RPW rows per wave share each Ut read. Gate inputs for step s+1
// prefetched before the k-loop (HBM latency hides under rec). Grid-stride
// over row-groups stages Ut once per block.
template<int WPB, int RPW>
__global__ __launch_bounds__(WPB * 64) void gru_reg(
    const float* __restrict__ xg,             // [dn*Nbatch, XGS] f32 (includes bi)
    const float* __restrict__ U,              // [50,150] f32
    const float* __restrict__ bias,           // [2,150] f32 (br = bias+150)
    float* __restrict__ Xout,                 // [MTOT,50] f32 time-major
    int dn, int Nbatch, int ngroups)
{
    constexpr int R = WPB * RPW;              // rows per block per group
    __shared__ __align__(16) float Ut[HH][HH][4];   // [k][unit][{z,r,h,0}] 40 KB

    const int tid  = threadIdx.x;
    const int wav  = tid >> 6;
    const int lane = tid & 63;

    for (int i = tid; i < HH * HH; i += WPB * 64)
        Ut[i / HH][i - (i / HH) * HH][3] = 0.f;
    for (int i = tid; i < HH * GG; i += WPB * 64) {
        int k = i / GG, cc = i - k * GG;
        Ut[k][cc % HH][cc / HH] = U[i];       // U cols: [z|r|h] blocks of 50
    }
    __syncthreads();                          // the only block-wide barrier

    const int c  = lane;
    const int cb = (c < HH) ? c : HH - 1;     // clamped for loads (lanes 50..63)

    const float bz  = bias[GG + cb];
    const float brr = bias[GG + HH + cb];
    const float bh  = bias[GG + 2 * HH + cb];

    for (int grp = blockIdx.x; grp < ngroups; grp += gridDim.x) {
        const int row0 = grp * R + wav * RPW;
        float h[RPW];
        #pragma unroll
        for (int j = 0; j < RPW; ++j) h[j] = 0.f;
        size_t obase[RPW];
        #pragma unroll
        for (int j = 0; j < RPW; ++j) {
            int nr = row0 + j;
            obase[j] = ((size_t)((nr >> 6) * dn) * NB + (nr & 63)) * HH + cb;
        }
        const float* gb = xg + (size_t)row0 * XGS;

        float px[RPW], pr[RPW], ph[RPW];
        #pragma unroll
        for (int j = 0; j < RPW; ++j) {       // preload step 0
            const float* g = gb + (size_t)j * XGS;
            px[j] = g[cb]; pr[j] = g[HH + cb]; ph[j] = g[2 * HH + cb];
        }

        for (int s = 0; s < dn; ++s) {
            // prefetch next step's gate inputs (lands during rec)
            const int sn = (s + 1 < dn) ? s + 1 : s;
            float nx[RPW], nrr[RPW], nh[RPW];
            #pragma unroll
            for (int j = 0; j < RPW; ++j) {
                const float* g = gb + ((size_t)sn * Nbatch + j) * XGS;
                nx[j] = g[cb]; nrr[j] = g[HH + cb]; nh[j] = g[2 * HH + cb];
            }
            // rec = h @ U + br, cols {c, 50+c, 100+c} -- all in registers
            float az[RPW], ar[RPW], ah[RPW];
            #pragma unroll
            for (int j = 0; j < RPW; ++j) { az[j] = bz; ar[j] = brr; ah[j] = bh; }
            #pragma unroll
            for (int k = 0; k < HH; ++k) {
                float4 w = *(const float4*)&Ut[k][c < HH ? c : 0][0];
                #pragma unroll
                for (int j = 0; j < RPW; ++j) {
                    float hk = bcast(h[j], k);
                    az[j] += hk * w.x;
                    ar[j] += hk * w.y;
                    ah[j] += hk * w.z;
                }
            }
            // gates + state update, all in registers
            #pragma unroll
            for (int j = 0; j < RPW; ++j) {
                float z  = sigm(px[j] + az[j]);
                float r  = sigm(pr[j] + ar[j]);
                float hh = tanh_f(ph[j] + r * ah[j]);
                float hn = z * h[j] + (1.f - z) * hh;
                h[j] = hn;
                if (c < HH) Xout[obase[j] + (size_t)s * NB * HH] = hn;
            }
            #pragma unroll
            for (int j = 0; j < RPW; ++j) { px[j] = nx[j]; pr[j] = nrr[j]; ph[j] = nh[j]; }
        }
    }
}

// ---------------- Head: split-K partial GEMM (no bias/relu here) ----------------
__global__ __launch_bounds__(256) void dense2_kernel(
    const float* __restrict__ X,              // [MTOT,50] f32 final layer (time-major)
    const float* __restrict__ W2,             // [1600,1600] f32
    float* __restrict__ part)                 // [16,64,1600] f32 partials
{
    __shared__ float fs[8][100];              // 3.2 KB
    const int tid = threadIdx.x;
    const int c  = blockIdx.x * 256 + tid;
    const int r0 = blockIdx.y * 8;
    const int kz = blockIdx.z;
    for (int i = tid; i < 8 * 100; i += 256) {
        int r = i / 100, fl = i - r * 100;
        int f = kz * 100 + fl, j = f / HH, k = f - j * HH;
        fs[r][fl] = X[((size_t)(TTT - 32 + j) * NB + (r0 + r)) * HH + k];
    }
    __syncthreads();
    if (c < 1600) {
        float a[8] = {0, 0, 0, 0, 0, 0, 0, 0};
        const float* w = W2 + (size_t)kz * 100 * 1600 + c;
        for (int fl = 0; fl < 100; ++fl) {
            float wv = w[(size_t)fl * 1600];
            #pragma unroll
            for (int r = 0; r < 8; ++r) a[r] += fs[r][fl] * wv;
        }
        #pragma unroll
        for (int r = 0; r < 8; ++r)
            part[((size_t)kz * NB + r0 + r) * 1600 + c] = a[r];
    }
}

// ---------------- Classifier: sum partials + bias + relu, then softmax ----------------
__global__ __launch_bounds__(256) void cls_kernel(
    const float* __restrict__ part,           // [16,64,1600] f32 partials
    const float* __restrict__ b2,             // [1600] f32
    const float* __restrict__ Wc,             // [1600,41] f32
    const float* __restrict__ bc,             // [41] f32
    float* __restrict__ out)                  // [64,41] f32
{
    __shared__ float hrow[1600];
    __shared__ float lg[41];
    __shared__ float red[2];
    const int b = blockIdx.x;
    const int t = threadIdx.x;
    for (int i = t; i < 1600; i += 256) {
        float s = b2[i];
        #pragma unroll 4
        for (int kz = 0; kz < 16; ++kz)
            s += part[((size_t)kz * NB + b) * 1600 + i];
        hrow[i] = s > 0.f ? s : 0.f;
    }
    __syncthreads();
    if (t < 41) {
        float acc = bc[t];
        for (int f = 0; f < 1600; ++f) acc += hrow[f] * Wc[f * 41 + t];
        lg[t] = acc;
    }
    __syncthreads();
    if (t == 0) {
        float mx = lg[0];
        for (int i = 1; i < 41; ++i) mx = fmaxf(mx, lg[i]);
        red[0] = mx;
    }
    __syncthreads();
    if (t < 41) lg[t] = expf(lg[t] - red[0]);
    __syncthreads();
    if (t == 0) {
        float sm = 0.f;
        for (int i = 0; i < 41; ++i) sm += lg[i];
        red[1] = 1.f / sm;
    }
    __syncthreads();
    if (t < 41) out[b * 41 + t] = lg[t] * red[1];
}

extern "C" void kernel_launch(void* const* d_in, const int* in_sizes, int n_in,
                              void* d_out, int out_size, void* d_ws, size_t ws_size,
                              hipStream_t stream)
{
    const float* x   = (const float*)d_in[0];    // [64,2048,128]
    const float* W0  = (const float*)d_in[1];    // [128,150]
    const float* U0  = (const float*)d_in[2];    // [50,150]
    const float* b0  = (const float*)d_in[3];    // [2,150]
    const float* Ws  = (const float*)d_in[4];    // [5,50,150]
    const float* Us  = (const float*)d_in[5];    // [5,50,150]
    const float* bs  = (const float*)d_in[6];    // [5,2,150]
    const float* W2  = (const float*)d_in[7];    // [1600,1600]
    const float* b2  = (const float*)d_in[8];    // [1600]
    const float* Wc  = (const float*)d_in[9];    // [1600,41]
    const float* bc  = (const float*)d_in[10];   // [41]

    float* xg   = (float*)d_ws;                       // MTOT*XGS f32  (79.7 MB)
    float* Xbuf = xg + (size_t)MTOT * XGS;            // MTOT*50 f32   (26.2 MB)
    float* part = xg;                                  // head partials reuse xg (6.6 MB)

    static const int rates[6] = {32, 64, 128, 256, 512, 1024};
    static const int rpws[6]  = {1, 1, 2, 2, 4, 4};    // rows/wave per layer

    proj0_kernel<<<dim3(MTOT / 128, 5), 256, 0, stream>>>(x, W0, b0, xg);
    {
        int dn = TTT / rates[0], Nbatch = rates[0] * NB;   // 64, 2048
        int ngroups = Nbatch / 4;                          // R=4 for <4,1>
        int grid = ngroups < 1024 ? ngroups : 1024;
        gru_reg<4, 1><<<grid, 256, 0, stream>>>(xg, U0, b0, Xbuf, dn, Nbatch, ngroups);
    }

    for (int l = 1; l < 6; ++l) {
        const float* Wl = Ws + (size_t)(l - 1) * HH * GG;
        const float* Ul = Us + (size_t)(l - 1) * HH * GG;
        const float* bl = bs + (size_t)(l - 1) * 2 * GG;
        projH_kernel<<<dim3(MTOT / 128, 5), 256, 0, stream>>>(Xbuf, Wl, bl, xg);
        int rate = rates[l];
        int Nbatch = rate * NB;
        int dn = TTT / rate;
        int rpw = rpws[l];
        int ngroups = Nbatch / (4 * rpw);
        int grid = ngroups < 1024 ? ngroups : 1024;
        if (rpw == 1)
            gru_reg<4, 1><<<grid, 256, 0, stream>>>(xg, Ul, bl, Xbuf, dn, Nbatch, ngroups);
        else if (rpw == 2)
            gru_reg<4, 2><<<grid, 256, 0, stream>>>(xg, Ul, bl, Xbuf, dn, Nbatch, ngroups);
        else
            gru_reg<4, 4><<<grid, 256, 0, stream>>>(xg, Ul, bl, Xbuf, dn, Nbatch, ngroups);
    }
    // head: split-K dense2 into partials (reuses xg), reduce+relu inside cls
    dense2_kernel<<<dim3(7, 8, 16), 256, 0, stream>>>(Xbuf, W2, part);
    cls_kernel<<<NB, 256, 0, stream>>>(part, b2, Wc, bc, (float*)d_out);
}